// Round 6
// baseline (288.370 us; speedup 1.0000x reference)
//
#include <hip/hip_runtime.h>
#include <math.h>

#define TMC 64   // cells per k_main block

typedef __attribute__((ext_vector_type(4))) float f32x4;
typedef __attribute__((ext_vector_type(8))) short bf16x8;

#define MFMA16(a,b,c) __builtin_amdgcn_mfma_f32_16x16x32_bf16((a),(b),(c),0,0,0)

__device__ __forceinline__ float sigmoidf_(float x){ return 1.0f/(1.0f + __expf(-x)); }
__device__ __forceinline__ float tanhf_(float x){
  float e = __expf(2.0f*x);
  return 1.0f - 2.0f/(e + 1.0f);
}

__device__ __forceinline__ unsigned short f2bf(float f){
  unsigned u = __float_as_uint(f);
  unsigned r = (u + 0x7FFFu + ((u>>16)&1u)) >> 16;
  return (unsigned short)r;
}
__device__ __forceinline__ unsigned pack2(float a, float b){
  return (unsigned)f2bf(a) | ((unsigned)f2bf(b)<<16);
}
__device__ __forceinline__ float bf2f(unsigned short u){ return __uint_as_float(((unsigned)u)<<16); }

__device__ __forceinline__ bf16x8 lds_ld8(const ushort* base, int byte){
  return *reinterpret_cast<const bf16x8*>(reinterpret_cast<const char*>(base) + byte);
}

// ---------- precompute: x-part of layer1 + combined biases (f32) ----------
__global__ void k_pre(const float* __restrict__ x,
                      const float* __restrict__ Wa1, const float* __restrict__ ba1,
                      const float* __restrict__ Wg1, const float* __restrict__ bg1,
                      const float* __restrict__ ba2, const float* __restrict__ bg2,
                      const float* __restrict__ bih, const float* __restrict__ bhh,
                      float* __restrict__ xab, float* __restrict__ b2d, float* __restrict__ brz){
  __shared__ float sx[64];
  int tid = threadIdx.x;
  if (tid < 64) sx[tid] = x[tid];
  __syncthreads();
  if (tid < 128){
    const float* w = Wa1 + tid*192;
    float s = ba1[tid];
    #pragma unroll
    for (int i=0;i<64;i++) s += w[i]*sx[i];
    xab[tid] = s;
  } else {
    int j = tid-128;
    const float* w = Wg1 + j*192;
    float s = bg1[j];
    #pragma unroll
    for (int i=0;i<64;i++) s += w[i]*sx[i];
    xab[tid] = s;
  }
  if (tid < 64) b2d[tid] = ba2[tid] - bg2[tid];
  brz[tid] = bih[tid] + bhh[tid];
}

// ---------- pack weights to bf16 fragment-contiguous layout ----------
// frag layout: elem(((nt*KS + ks)*64 + lane)*8 + e) = W[nt*16 + (lane&15)][ks*32 + (lane>>4)*8 + e]
__global__ void k_pack(const float* __restrict__ Wa1, const float* __restrict__ Wg1,
                       const float* __restrict__ Wa2, const float* __restrict__ Wg2,
                       const float* __restrict__ Wih, const float* __restrict__ Whh,
                       ushort* __restrict__ W1f, ushort* __restrict__ W2f,
                       ushort* __restrict__ Wgf, ushort* __restrict__ Whf,
                       float* __restrict__ w64){
  int stride = gridDim.x*blockDim.x;
  int t0 = blockIdx.x*blockDim.x + threadIdx.x;
  for (int i=t0; i<256*128; i+=stride){
    int e=i&7, lane=(i>>3)&63, ks=(i>>9)&3, nt=i>>11;
    int r = nt*16 + (lane&15), k = ks*32 + (lane>>4)*8 + e;
    float v = (r<128) ? Wa1[r*192+64+k] : Wg1[(r-128)*192+64+k];
    W1f[i] = f2bf(v);
  }
  for (int i=t0; i<128*128; i+=stride){
    int e=i&7, lane=(i>>3)&63, ks=(i>>9)&3, nt=i>>11;
    int r = nt*16 + (lane&15), k = ks*32 + (lane>>4)*8 + e;
    float v = (r<64) ? Wa2[r*128+k] : Wg2[(r-64)*128+k];
    W2f[i] = f2bf(v);
  }
  for (int i=t0; i<384*64; i+=stride){
    int e=i&7, lane=(i>>3)&63, ks=(i>>9)&1, nt=i>>10;
    int r = nt*16 + (lane&15), k = ks*32 + (lane>>4)*8 + e;
    Wgf[i] = f2bf(Wih[r*65+k]);
  }
  for (int i=t0; i<384*128; i+=stride){
    int e=i&7, lane=(i>>3)&63, ks=(i>>9)&3, nt=i>>11;
    int r = nt*16 + (lane&15), k = ks*32 + (lane>>4)*8 + e;
    Whf[i] = f2bf(Whh[r*128+k]);
  }
  for (int i=t0; i<384; i+=stride) w64[i] = Wih[i*65+64];
}

// ---------- mark alive ordinals ----------
__global__ void k_mark(const int* __restrict__ alive, int* __restrict__ iflags, int n){
  int i = blockIdx.x*blockDim.x + threadIdx.x;
  if (i < n) iflags[alive[i]] = i + 1;
}

// GRU gate GEMM accumulate into acc[4 M-tiles], single N-tile
template<bool DOMEM, bool DOH>
__device__ __forceinline__ void gru_accum1(f32x4 (&acc)[4],
    const ushort* sMIH, const ushort* sH,
    const ushort* __restrict__ Wgf, const ushort* __restrict__ Whf,
    int nt, int lane, int l15, int lg)
{
  if (DOMEM){
    #pragma unroll
    for (int ks=0; ks<2; ks++){
      bf16x8 a[4];
      #pragma unroll
      for (int tm=0; tm<4; tm++){
        int row = tm*16 + l15;
        a[tm] = lds_ld8(sMIH, (row*128 + ks*64 + lg*16) ^ ((row&7)<<4));
      }
      bf16x8 b = *(const bf16x8*)(Wgf + (((nt*2 + ks)*64 + lane)<<3));
      #pragma unroll
      for (int tm=0; tm<4; tm++)
        acc[tm] = MFMA16(a[tm], b, acc[tm]);
    }
  }
  if (DOH){
    #pragma unroll
    for (int ks=0; ks<4; ks++){
      bf16x8 a[4];
      #pragma unroll
      for (int tm=0; tm<4; tm++){
        int row = tm*16 + l15;
        a[tm] = lds_ld8(sH, (row*256 + ks*64 + lg*16) ^ ((row&7)<<4));
      }
      bf16x8 b = *(const bf16x8*)(Whf + (((nt*4 + ks)*64 + lane)<<3));
      #pragma unroll
      for (int tm=0; tm<4; tm++)
        acc[tm] = MFMA16(a[tm], b, acc[tm]);
    }
  }
}

// ---------- main MFMA kernel: 64 cells / block, 4 waves, 3 blocks/CU ----------
__global__ __launch_bounds__(256,3) void k_main(
    const float* __restrict__ hiddens, const int* __restrict__ alive,
    const ushort* __restrict__ W1f, const ushort* __restrict__ W2f,
    const ushort* __restrict__ Wgf, const ushort* __restrict__ Whf,
    const float* __restrict__ w64,
    const float* __restrict__ xab, const float* __restrict__ b2d,
    const float* __restrict__ brz,
    const float* __restrict__ bih, const float* __restrict__ bhh,
    float* __restrict__ nh, float* __restrict__ facsum,
    float* __restrict__ recs, unsigned* __restrict__ tmax_u, float* __restrict__ tsum,
    int n, int fs, int nffs)
{
  __shared__ ushort sH[64*128];                   // 16 KB bf16, swizzled, stride 256B
  __shared__ __align__(16) ushort arena[64*256];  // 32 KB: sV1 (bf16 512B) -> sMIH (bf16 128B) -> sStage (f32 512B)
  __shared__ float sTS[4][64];
  __shared__ float sT[64];
  __shared__ float sE[64];
  __shared__ int   sIdx[TMC];

  ushort* sV1  = arena;             // [64][256] bf16 during GEMM1/2
  ushort* sMIH = arena;             // [64][64]  bf16 during GRU accums
  float*  sStage = (float*)arena;   // [64][128] f32 after GRU accums

  int tid = threadIdx.x;
  int lane = tid & 63;
  int w = tid >> 6;
  int l15 = lane & 15;
  int lg  = lane >> 4;

  int base = blockIdx.x * TMC;
  int nvalid = n - base; if (nvalid > TMC) nvalid = TMC;

  if (tid < TMC){
    int t2 = tid < nvalid ? tid : (nvalid-1);
    sIdx[tid] = alive[base + t2];
  }
  __syncthreads();

  // ---- stage h -> bf16 LDS (swizzled)
  {
    int m = tid >> 2, c0 = (tid & 3) * 32;
    const float* src = hiddens + (size_t)sIdx[m]*128 + c0;
    #pragma unroll
    for (int j=0; j<32; j+=8){
      float4 v0 = *(const float4*)(src + j);
      float4 v1 = *(const float4*)(src + j + 4);
      uint4 pk;
      pk.x = pack2(v0.x, v0.y); pk.y = pack2(v0.z, v0.w);
      pk.z = pack2(v1.x, v1.y); pk.w = pack2(v1.z, v1.w);
      int byte = (m*256 + (c0 + j)*2) ^ ((m&7)<<4);
      *reinterpret_cast<uint4*>(reinterpret_cast<char*>(sH) + byte) = pk;
    }
  }
  __syncthreads();

  // ---- GEMM1: v1 = relu(h @ W1h^T + xab); wave w -> cols [w*64, w*64+64)
  {
    int c0 = w*64;
    f32x4 acc[4][4];
    #pragma unroll
    for (int tm=0;tm<4;tm++)
      #pragma unroll
      for (int tn=0;tn<4;tn++) acc[tm][tn] = (f32x4)0.f;
    #pragma unroll
    for (int ks=0; ks<4; ks++){
      bf16x8 a[4], b[4];
      #pragma unroll
      for (int tm=0;tm<4;tm++){
        int row = tm*16 + l15;
        a[tm] = lds_ld8(sH, (row*256 + ks*64 + lg*16) ^ ((row&7)<<4));
      }
      #pragma unroll
      for (int tn=0;tn<4;tn++)
        b[tn] = *(const bf16x8*)(W1f + ((((w*4+tn)*4 + ks)*64 + lane)<<3));
      #pragma unroll
      for (int tm=0;tm<4;tm++)
        #pragma unroll
        for (int tn=0;tn<4;tn++)
          acc[tm][tn] = MFMA16(a[tm], b[tn], acc[tm][tn]);
    }
    #pragma unroll
    for (int tn=0;tn<4;tn++){
      int col = c0 + tn*16 + l15;
      float bias = xab[col];
      #pragma unroll
      for (int tm=0;tm<4;tm++){
        #pragma unroll
        for (int r=0;r<4;r++){
          int row = tm*16 + lg*4 + r;
          float v = fmaxf(acc[tm][tn][r] + bias, 0.f);
          int byte = (row*512 + col*2) ^ ((row&7)<<4);
          *(ushort*)((char*)sV1 + byte) = f2bf(v);
        }
      }
    }
  }
  __syncthreads();

  // ---- GEMM2: out = a - g; wave w -> out cols [w*16, w*16+16)
  int jo2 = w*16;
  float outv[4][4];
  {
    f32x4 accA[4], accG[4];
    #pragma unroll
    for (int tm=0;tm<4;tm++){ accA[tm]=(f32x4)0.f; accG[tm]=(f32x4)0.f; }
    #pragma unroll
    for (int ks=0; ks<4; ks++){
      bf16x8 aA[4], aG[4], bA, bG;
      #pragma unroll
      for (int tm=0;tm<4;tm++){
        int row = tm*16 + l15;
        aA[tm] = lds_ld8(sV1, (row*512 + ks*64 + lg*16) ^ ((row&7)<<4));
        aG[tm] = lds_ld8(sV1, (row*512 + 256 + ks*64 + lg*16) ^ ((row&7)<<4));
      }
      bA = *(const bf16x8*)(W2f + (((w*4 + ks)*64 + lane)<<3));
      bG = *(const bf16x8*)(W2f + ((((4+w)*4 + ks)*64 + lane)<<3));
      #pragma unroll
      for (int tm=0;tm<4;tm++){
        accA[tm] = MFMA16(aA[tm], bA, accA[tm]);
        accG[tm] = MFMA16(aG[tm], bG, accG[tm]);
      }
    }
    int col = jo2 + l15;
    float bias = b2d[col];
    #pragma unroll
    for (int tm=0;tm<4;tm++)
      #pragma unroll
      for (int r=0;r<4;r++)
        outv[tm][r] = accA[tm][r] - accG[tm][r] + bias;
  }
  __syncthreads();   // all sV1 reads done; arena reusable as sMIH

  // ---- epilogue: write out (bf16, K=64 layout) + per-wave tension partials
  {
    int col = jo2 + l15;
    float p[4][4];
    #pragma unroll
    for (int tm=0;tm<4;tm++){
      #pragma unroll
      for (int r=0;r<4;r++){
        int row = tm*16 + lg*4 + r;
        float o = outv[tm][r];
        int byte = (row*128 + col*2) ^ ((row&7)<<4);
        *(ushort*)((char*)sMIH + byte) = f2bf(o);
        p[tm][r] = o*o;
      }
    }
    #pragma unroll
    for (int off=1; off<16; off<<=1)
      #pragma unroll
      for (int tm=0;tm<4;tm++)
        #pragma unroll
        for (int r=0;r<4;r++) p[tm][r] += __shfl_xor(p[tm][r], off);
    if (l15 == 0){
      #pragma unroll
      for (int tm=0;tm<4;tm++)
        #pragma unroll
        for (int r=0;r<4;r++) sTS[w][tm*16 + lg*4 + r] = p[tm][r];
    }
  }
  __syncthreads();

  // ---- tension stats (wave 0; 64 lanes <-> 64 rows)
  if (w == 0){
    int row = lane;
    float t = (sTS[0][row] + sTS[1][row] + sTS[2][row] + sTS[3][row]) * (1.0f/64.0f);
    sT[row] = t;
    bool valid = row < nvalid;
    float m2 = valid ? t : -1.f;
    #pragma unroll
    for (int off=1; off<64; off<<=1) m2 = fmaxf(m2, __shfl_xor(m2, off));
    float e  = valid ? __expf(t - m2) : 0.f;
    float st = valid ? t : 0.f;
    float se = e, ss = st;
    #pragma unroll
    for (int off=1; off<64; off<<=1){ se += __shfl_xor(se, off); ss += __shfl_xor(ss, off); }
    sE[row] = e;
    if (lane == 0){
      float* rec = recs + (size_t)blockIdx.x*66;
      rec[0] = m2; rec[1] = se;
      atomicMax(tmax_u, __float_as_uint(m2));   // t >= 0
      atomicAdd(tsum, ss);
    }
  }
  __syncthreads();

  // ---- block-local softmax numerator (from registers)
  {
    float np = 0.f;
    #pragma unroll
    for (int tm=0;tm<4;tm++)
      #pragma unroll
      for (int r=0;r<4;r++)
        np += sE[tm*16 + lg*4 + r] * outv[tm][r];
    np += __shfl_xor(np, 16);
    np += __shfl_xor(np, 32);
    if (lg == 0) recs[(size_t)blockIdx.x*66 + 2 + jo2 + l15] = np;
  }

  // ---- load tension per-row into regs
  float t16v[4][4];
  #pragma unroll
  for (int tm=0;tm<4;tm++)
    #pragma unroll
    for (int r=0;r<4;r++) t16v[tm][r] = sT[tm*16 + lg*4 + r];

  // ---- faction bookkeeping (block-level)
  int lastrow = nvalid;
  if (base + lastrow > nffs) lastrow = nffs - base;
  int f0 = (fs > 0 && base < nffs) ? base / fs : 0;
  bool onefac = (lastrow <= 0) || ((base + lastrow - 1) / fs == f0);

  // ---- GRU: two passes; wave w -> hidden cols [(p*4+w)*16, +16); results in regs
  float vout[2][4][4];
  #pragma unroll
  for (int p=0; p<2; p++){
    int colt = p*4 + w;
    int col  = colt*16 + l15;
    // hn pre-activation (h part of candidate)
    f32x4 hnA[4];
    #pragma unroll
    for (int tm=0;tm<4;tm++) hnA[tm] = (f32x4)0.f;
    gru_accum1<false,true>(hnA, sMIH, sH, Wgf, Whf, 16 + colt, lane, l15, lg);
    // r gate -> fold into hnA = r*(hn + bhh_n)
    {
      f32x4 gA[4];
      #pragma unroll
      for (int tm=0;tm<4;tm++) gA[tm] = (f32x4)0.f;
      gru_accum1<true,true>(gA, sMIH, sH, Wgf, Whf, colt, lane, l15, lg);
      float b = brz[col], wv = w64[col], bhn = bhh[256+col];
      #pragma unroll
      for (int tm=0;tm<4;tm++)
        #pragma unroll
        for (int r=0;r<4;r++){
          float rr = sigmoidf_(gA[tm][r] + b + t16v[tm][r]*wv);
          hnA[tm][r] = rr * (hnA[tm][r] + bhn);
        }
    }
    // z gate
    f32x4 zA[4];
    #pragma unroll
    for (int tm=0;tm<4;tm++) zA[tm] = (f32x4)0.f;
    gru_accum1<true,true>(zA, sMIH, sH, Wgf, Whf, 8 + colt, lane, l15, lg);
    {
      float b = brz[128+col], wv = w64[128+col];
      #pragma unroll
      for (int tm=0;tm<4;tm++)
        #pragma unroll
        for (int r=0;r<4;r++)
          zA[tm][r] = sigmoidf_(zA[tm][r] + b + t16v[tm][r]*wv);
    }
    // inn (mem part of candidate)
    f32x4 iA[4];
    #pragma unroll
    for (int tm=0;tm<4;tm++) iA[tm] = (f32x4)0.f;
    gru_accum1<true,false>(iA, sMIH, sH, Wgf, Whf, 16 + colt, lane, l15, lg);

    // final combine (to regs) + faction sums
    {
      float bi = bih[256+col], wv = w64[256+col];
      float fsum = 0.f;
      #pragma unroll
      for (int tm=0;tm<4;tm++){
        #pragma unroll
        for (int r=0;r<4;r++){
          int row = tm*16 + lg*4 + r;
          float nnv = tanhf_(iA[tm][r] + bi + t16v[tm][r]*wv + hnA[tm][r]);
          int hb = (row*256 + col*2) ^ ((row&7)<<4);
          float hv = bf2f(*(const ushort*)((const char*)sH + hb));
          float zv = zA[tm][r];
          float v = (1.f - zv)*nnv + zv*hv;
          vout[p][tm][r] = v;
          if (onefac){
            if (row < lastrow) fsum += v;
          } else if (row < lastrow){
            atomicAdd(&facsum[((base+row)/fs)*128 + col], v);
          }
        }
      }
      if (onefac && lastrow > 0){
        fsum += __shfl_xor(fsum, 16);
        fsum += __shfl_xor(fsum, 32);
        if (lg == 0) atomicAdd(&facsum[f0*128 + col], fsum);
      }
    }
  }
  __syncthreads();   // all waves' sMIH reads done; arena becomes f32 stage

  // ---- stage v -> f32 LDS (swizzled)
  #pragma unroll
  for (int p=0; p<2; p++){
    int col = (p*4 + w)*16 + l15;
    #pragma unroll
    for (int tm=0;tm<4;tm++){
      #pragma unroll
      for (int r=0;r<4;r++){
        int row = tm*16 + lg*4 + r;
        int sb = (row*512 + col*4) ^ ((row&7)<<4);
        *(float*)((char*)sStage + sb) = vout[p][tm][r];
      }
    }
  }
  __syncthreads();

  // ---- coalesced scatter: each row written once, contiguously
  for (int e = tid; e < TMC*128; e += 256){
    int m = e >> 7, j = e & 127;
    if (m < nvalid){
      int sb = (m*512 + j*4) ^ ((m&7)<<4);
      nh[(size_t)sIdx[m]*128 + j] = *(const float*)((const char*)sStage + sb);
    }
  }
}

// ---------- combine per-block softmax records ----------
__global__ void k_comb1(const float* __restrict__ recs, int nrec,
                        const unsigned* __restrict__ tmax_u,
                        float* __restrict__ num, float* __restrict__ S){
  int tid = threadIdx.x;
  int c = tid & 63, rg = tid >> 6;
  float M = __uint_as_float(*tmax_u);
  float acc = 0.f, sacc = 0.f;
  for (int r = blockIdx.x*4 + rg; r < nrec; r += gridDim.x*4){
    const float* rec = recs + (size_t)r*66;
    float e = __expf(rec[0] - M);
    acc += e * rec[2+c];
    if (c == 0) sacc += e * rec[1];
  }
  __shared__ float sn[4][64];
  __shared__ float ss[4];
  sn[rg][c] = acc;
  if (c == 0) ss[rg] = sacc;
  __syncthreads();
  if (tid < 64) atomicAdd(&num[tid], sn[0][tid]+sn[1][tid]+sn[2][tid]+sn[3][tid]);
  if (tid == 64) atomicAdd(S, ss[0]+ss[1]+ss[2]+ss[3]);
}

// ---------- finalize combined / mean_tension / faction means ----------
__global__ void k_final(const float* __restrict__ num, const float* __restrict__ S,
                        const float* __restrict__ tsum, const float* __restrict__ facsum,
                        float* __restrict__ out, float* __restrict__ go, float* __restrict__ fmn,
                        int n, int n_f, int fs){
  int tid = threadIdx.x;
  if (tid < 64) out[tid] = num[tid] / *S;
  else if (tid == 64) out[64] = *tsum / (float)n;
  if (tid >= 128 && n_f >= 2){
    int j = tid - 128;
    float s = 0.f;
    for (int f=0; f<n_f; f++){
      float v = facsum[f*128+j];
      s += v;
      fmn[f*128+j] = v / (float)fs;
    }
    go[j] = s / (float)(n_f*fs);
  }
}

// ---------- fused post-pass: copy non-alive rows + faction RMW on alive rows ----------
__global__ void k_post(const float* __restrict__ hid, const int* __restrict__ iflags,
                       const float* __restrict__ fmn, const float* __restrict__ go,
                       const int* __restrict__ step_p,
                       float* __restrict__ nh, int fs, int dc, int nffs, int total){
  bool debate = (*step_p > 5);
  int stride = gridDim.x*blockDim.x;
  for (int idx = blockIdx.x*blockDim.x + threadIdx.x; idx < total; idx += stride){
    int c = idx >> 5, q = idx & 31, j0 = q*4;
    size_t off = (size_t)c*128 + j0;
    int fl = iflags[c];
    if (fl == 0){
      float4 h4 = *(const float4*)(hid + off);
      nh[off] = h4.x; nh[off+1] = h4.y; nh[off+2] = h4.z; nh[off+3] = h4.w;
    } else {
      int i = fl - 1;
      if (i < nffs){
        float v0 = nh[off], v1 = nh[off+1], v2 = nh[off+2], v3 = nh[off+3];
        int f = i / fs;
        float4 fm4 = *(const float4*)(fmn + f*128 + j0);
        v0 = 0.85f*v0 + 0.15f*fm4.x;
        v1 = 0.85f*v1 + 0.15f*fm4.y;
        v2 = 0.85f*v2 + 0.15f*fm4.z;
        v3 = 0.85f*v3 + 0.15f*fm4.w;
        if (debate && (i - f*fs) < dc){
          float4 g4 = *(const float4*)(go + j0);
          v0 = 0.85f*v0 + 0.15f*g4.x;
          v1 = 0.85f*v1 + 0.15f*g4.y;
          v2 = 0.85f*v2 + 0.15f*g4.z;
          v3 = 0.85f*v3 + 0.15f*g4.w;
        }
        nh[off] = v0; nh[off+1] = v1; nh[off+2] = v2; nh[off+3] = v3;
      }
      // alive beyond faction region: value already correct in nh
    }
  }
}

extern "C" void kernel_launch(void* const* d_in, const int* in_sizes, int n_in,
                              void* d_out, int out_size, void* d_ws, size_t ws_size,
                              hipStream_t stream){
  const float* x    = (const float*)d_in[0];
  const float* hid  = (const float*)d_in[1];
  const float* Wa1  = (const float*)d_in[2];
  const float* ba1  = (const float*)d_in[3];
  const float* Wa2  = (const float*)d_in[4];
  const float* ba2  = (const float*)d_in[5];
  const float* Wg1  = (const float*)d_in[6];
  const float* bg1  = (const float*)d_in[7];
  const float* Wg2  = (const float*)d_in[8];
  const float* bg2  = (const float*)d_in[9];
  const float* Wih  = (const float*)d_in[10];
  const float* Whh  = (const float*)d_in[11];
  const float* bih  = (const float*)d_in[12];
  const float* bhh  = (const float*)d_in[13];
  const int*   alive= (const int*)d_in[14];
  const int*   step = (const int*)d_in[15];

  int n = in_sizes[14];
  int n_cells = in_sizes[1] / 128;
  int n_f = (n/2 < 8) ? n/2 : 8;
  int fs   = (n_f >= 2) ? n / n_f : 0;
  int nffs = (n_f >= 2) ? n_f * fs : 0;
  int dc   = (fs/4 > 1) ? fs/4 : 1;
  int nblocks = (n + TMC - 1) / TMC;

  float* out = (float*)d_out;
  float* nh  = out + 65;          // new_hiddens region (4B-aligned only!)
  float* ws  = (float*)d_ws;

  float* xab   = ws + 0;          // 256
  float* b2d   = ws + 256;        // 64
  float* brz   = ws + 320;        // 256
  float* facs  = ws + 576;        // 1024
  float* num   = ws + 1600;       // 64
  float* Ssum  = ws + 1664;       // 1
  float* tsum  = ws + 1665;       // 1
  unsigned* tmax_u = (unsigned*)(ws + 1666);  // 1 (+1 pad)
  float* go    = ws + 1668;       // 128
  float* fmn   = ws + 1796;       // 1024
  float* w64   = ws + 2820;       // 384
  float* recs  = ws + 3204;       // nblocks*66
  int recs_end = 3204 + ((nblocks*66 + 3) & ~3);
  int* iflags  = (int*)(ws + recs_end);                  // n_cells
  int woff = (recs_end + n_cells + 3) & ~3;
  ushort* W1f  = (ushort*)(ws + woff);                   // 256*128 bf16 = 16384 f
  ushort* W2f  = (ushort*)(ws + woff + 16384);           // 128*128 bf16 = 8192 f
  ushort* Wgf  = (ushort*)(ws + woff + 24576);           // 384*64  bf16 = 12288 f
  ushort* Whf  = (ushort*)(ws + woff + 36864);           // 384*128 bf16 = 24576 f

  // zero atomic accumulators (facs..tmax+pad) and iflags
  hipMemsetAsync(ws + 576, 0, 1092*sizeof(float), stream);
  hipMemsetAsync(iflags, 0, (size_t)n_cells*sizeof(int), stream);

  k_pre<<<1,256,0,stream>>>(x, Wa1, ba1, Wg1, bg1, ba2, bg2, bih, bhh, xab, b2d, brz);
  k_pack<<<256,256,0,stream>>>(Wa1, Wg1, Wa2, Wg2, Wih, Whh, W1f, W2f, Wgf, Whf, w64);
  k_mark<<<(n+255)/256,256,0,stream>>>(alive, iflags, n);
  k_main<<<nblocks,256,0,stream>>>(hid, alive, W1f, W2f, Wgf, Whf, w64, xab, b2d, brz,
                                   bih, bhh, nh, facs, recs, tmax_u, tsum,
                                   n, fs, nffs);
  k_comb1<<<64,256,0,stream>>>(recs, nblocks, tmax_u, num, Ssum);
  k_final<<<1,256,0,stream>>>(num, Ssum, tsum, facs, out, go, fmn, n, n_f, fs);
  k_post<<<2048,256,0,stream>>>(hid, iflags, fmn, go, step, nh, fs, dc, nffs, n_cells*32);
}

// Round 7
// 183.445 us; speedup vs baseline: 1.5720x; 1.5720x over previous
//
#include <hip/hip_runtime.h>
#include <math.h>

#define TMC 64   // cells per k_main block

typedef __attribute__((ext_vector_type(4))) float f32x4;
typedef __attribute__((ext_vector_type(8))) short bf16x8;

#define MFMA16(a,b,c) __builtin_amdgcn_mfma_f32_16x16x32_bf16((a),(b),(c),0,0,0)

__device__ __forceinline__ float sigmoidf_(float x){ return 1.0f/(1.0f + __expf(-x)); }
__device__ __forceinline__ float tanhf_(float x){
  float e = __expf(2.0f*x);
  return 1.0f - 2.0f/(e + 1.0f);
}

__device__ __forceinline__ unsigned short f2bf(float f){
  unsigned u = __float_as_uint(f);
  unsigned r = (u + 0x7FFFu + ((u>>16)&1u)) >> 16;
  return (unsigned short)r;
}
__device__ __forceinline__ unsigned pack2(float a, float b){
  return (unsigned)f2bf(a) | ((unsigned)f2bf(b)<<16);
}
__device__ __forceinline__ float bf2f(unsigned short u){ return __uint_as_float(((unsigned)u)<<16); }

__device__ __forceinline__ bf16x8 lds_ld8(const ushort* base, int byte){
  return *reinterpret_cast<const bf16x8*>(reinterpret_cast<const char*>(base) + byte);
}

// ---------- precompute: x-part of layer1 + combined biases (f32) ----------
__global__ void k_pre(const float* __restrict__ x,
                      const float* __restrict__ Wa1, const float* __restrict__ ba1,
                      const float* __restrict__ Wg1, const float* __restrict__ bg1,
                      const float* __restrict__ ba2, const float* __restrict__ bg2,
                      const float* __restrict__ bih, const float* __restrict__ bhh,
                      float* __restrict__ xab, float* __restrict__ b2d, float* __restrict__ brz){
  __shared__ float sx[64];
  int tid = threadIdx.x;
  if (tid < 64) sx[tid] = x[tid];
  __syncthreads();
  if (tid < 128){
    const float* w = Wa1 + tid*192;
    float s = ba1[tid];
    #pragma unroll
    for (int i=0;i<64;i++) s += w[i]*sx[i];
    xab[tid] = s;
  } else {
    int j = tid-128;
    const float* w = Wg1 + j*192;
    float s = bg1[j];
    #pragma unroll
    for (int i=0;i<64;i++) s += w[i]*sx[i];
    xab[tid] = s;
  }
  if (tid < 64) b2d[tid] = ba2[tid] - bg2[tid];
  brz[tid] = bih[tid] + bhh[tid];
}

// ---------- pack weights to bf16 fragment-contiguous layout ----------
// frag layout: elem(((nt*KS + ks)*64 + lane)*8 + e) = W[nt*16 + (lane&15)][ks*32 + (lane>>4)*8 + e]
__global__ void k_pack(const float* __restrict__ Wa1, const float* __restrict__ Wg1,
                       const float* __restrict__ Wa2, const float* __restrict__ Wg2,
                       const float* __restrict__ Wih, const float* __restrict__ Whh,
                       ushort* __restrict__ W1f, ushort* __restrict__ W2f,
                       ushort* __restrict__ Wgf, ushort* __restrict__ Whf,
                       float* __restrict__ w64){
  int stride = gridDim.x*blockDim.x;
  int t0 = blockIdx.x*blockDim.x + threadIdx.x;
  for (int i=t0; i<256*128; i+=stride){
    int e=i&7, lane=(i>>3)&63, ks=(i>>9)&3, nt=i>>11;
    int r = nt*16 + (lane&15), k = ks*32 + (lane>>4)*8 + e;
    float v = (r<128) ? Wa1[r*192+64+k] : Wg1[(r-128)*192+64+k];
    W1f[i] = f2bf(v);
  }
  for (int i=t0; i<128*128; i+=stride){
    int e=i&7, lane=(i>>3)&63, ks=(i>>9)&3, nt=i>>11;
    int r = nt*16 + (lane&15), k = ks*32 + (lane>>4)*8 + e;
    float v = (r<64) ? Wa2[r*128+k] : Wg2[(r-64)*128+k];
    W2f[i] = f2bf(v);
  }
  for (int i=t0; i<384*64; i+=stride){
    int e=i&7, lane=(i>>3)&63, ks=(i>>9)&1, nt=i>>10;
    int r = nt*16 + (lane&15), k = ks*32 + (lane>>4)*8 + e;
    Wgf[i] = f2bf(Wih[r*65+k]);
  }
  for (int i=t0; i<384*128; i+=stride){
    int e=i&7, lane=(i>>3)&63, ks=(i>>9)&3, nt=i>>11;
    int r = nt*16 + (lane&15), k = ks*32 + (lane>>4)*8 + e;
    Whf[i] = f2bf(Whh[r*128+k]);
  }
  for (int i=t0; i<384; i+=stride) w64[i] = Wih[i*65+64];
}

// ---------- mark alive ordinals ----------
__global__ void k_mark(const int* __restrict__ alive, int* __restrict__ iflags, int n){
  int i = blockIdx.x*blockDim.x + threadIdx.x;
  if (i < n) iflags[alive[i]] = i + 1;
}

// ---------- main MFMA kernel: 64 cells / block, 4 waves, 2 blocks/CU (spill-free) ----------
__global__ __launch_bounds__(256,2) void k_main(
    const float* __restrict__ hiddens, const int* __restrict__ alive,
    const ushort* __restrict__ W1f, const ushort* __restrict__ W2f,
    const ushort* __restrict__ Wgf, const ushort* __restrict__ Whf,
    const float* __restrict__ w64,
    const float* __restrict__ xab, const float* __restrict__ b2d,
    const float* __restrict__ brz,
    const float* __restrict__ bih, const float* __restrict__ bhh,
    float* __restrict__ nh, float* __restrict__ facsum,
    float* __restrict__ recs, unsigned* __restrict__ tmax_u, float* __restrict__ tsum,
    int n, int fs, int nffs)
{
  __shared__ ushort sH[64*128];                   // 16 KB bf16, swizzled, stride 256B
  __shared__ __align__(16) ushort arena[64*256];  // 32 KB: sV1 (bf16 512B) -> sMIH (bf16 128B)
  __shared__ float sTS[4][64];
  __shared__ float sT[64];
  __shared__ float sE[64];
  __shared__ int   sIdx[TMC];

  ushort* sV1  = arena;             // [64][256] bf16 during GEMM1/2
  ushort* sMIH = arena;             // [64][64]  bf16 during GRU

  int tid = threadIdx.x;
  int lane = tid & 63;
  int w = tid >> 6;
  int l15 = lane & 15;
  int lg  = lane >> 4;

  int base = blockIdx.x * TMC;
  int nvalid = n - base; if (nvalid > TMC) nvalid = TMC;

  if (tid < TMC){
    int t2 = tid < nvalid ? tid : (nvalid-1);
    sIdx[tid] = alive[base + t2];
  }
  __syncthreads();

  // ---- stage h -> bf16 LDS (swizzled)
  {
    int m = tid >> 2, c0 = (tid & 3) * 32;
    const float* src = hiddens + (size_t)sIdx[m]*128 + c0;
    #pragma unroll
    for (int j=0; j<32; j+=8){
      float4 v0 = *(const float4*)(src + j);
      float4 v1 = *(const float4*)(src + j + 4);
      uint4 pk;
      pk.x = pack2(v0.x, v0.y); pk.y = pack2(v0.z, v0.w);
      pk.z = pack2(v1.x, v1.y); pk.w = pack2(v1.z, v1.w);
      int byte = (m*256 + (c0 + j)*2) ^ ((m&7)<<4);
      *reinterpret_cast<uint4*>(reinterpret_cast<char*>(sH) + byte) = pk;
    }
  }
  __syncthreads();

  // ---- GEMM1: v1 = relu(h @ W1h^T + xab); wave w -> cols [w*64, w*64+64)
  {
    int c0 = w*64;
    f32x4 acc[4][4];
    #pragma unroll
    for (int tm=0;tm<4;tm++)
      #pragma unroll
      for (int tn=0;tn<4;tn++) acc[tm][tn] = (f32x4)0.f;
    #pragma unroll
    for (int ks=0; ks<4; ks++){
      bf16x8 a[4], b[4];
      #pragma unroll
      for (int tm=0;tm<4;tm++){
        int row = tm*16 + l15;
        a[tm] = lds_ld8(sH, (row*256 + ks*64 + lg*16) ^ ((row&7)<<4));
      }
      #pragma unroll
      for (int tn=0;tn<4;tn++)
        b[tn] = *(const bf16x8*)(W1f + ((((w*4+tn)*4 + ks)*64 + lane)<<3));
      #pragma unroll
      for (int tm=0;tm<4;tm++)
        #pragma unroll
        for (int tn=0;tn<4;tn++)
          acc[tm][tn] = MFMA16(a[tm], b[tn], acc[tm][tn]);
    }
    #pragma unroll
    for (int tn=0;tn<4;tn++){
      int col = c0 + tn*16 + l15;
      float bias = xab[col];
      #pragma unroll
      for (int tm=0;tm<4;tm++){
        #pragma unroll
        for (int r=0;r<4;r++){
          int row = tm*16 + lg*4 + r;
          float v = fmaxf(acc[tm][tn][r] + bias, 0.f);
          int byte = (row*512 + col*2) ^ ((row&7)<<4);
          *(ushort*)((char*)sV1 + byte) = f2bf(v);
        }
      }
    }
  }
  __syncthreads();

  // ---- GEMM2: out = a - g; wave w -> out cols [w*16, w*16+16)
  int jo2 = w*16;
  float outv[4][4];
  {
    f32x4 accA[4], accG[4];
    #pragma unroll
    for (int tm=0;tm<4;tm++){ accA[tm]=(f32x4)0.f; accG[tm]=(f32x4)0.f; }
    #pragma unroll
    for (int ks=0; ks<4; ks++){
      bf16x8 aA[4], aG[4], bA, bG;
      #pragma unroll
      for (int tm=0;tm<4;tm++){
        int row = tm*16 + l15;
        aA[tm] = lds_ld8(sV1, (row*512 + ks*64 + lg*16) ^ ((row&7)<<4));
        aG[tm] = lds_ld8(sV1, (row*512 + 256 + ks*64 + lg*16) ^ ((row&7)<<4));
      }
      bA = *(const bf16x8*)(W2f + (((w*4 + ks)*64 + lane)<<3));
      bG = *(const bf16x8*)(W2f + ((((4+w)*4 + ks)*64 + lane)<<3));
      #pragma unroll
      for (int tm=0;tm<4;tm++){
        accA[tm] = MFMA16(aA[tm], bA, accA[tm]);
        accG[tm] = MFMA16(aG[tm], bG, accG[tm]);
      }
    }
    int col = jo2 + l15;
    float bias = b2d[col];
    #pragma unroll
    for (int tm=0;tm<4;tm++)
      #pragma unroll
      for (int r=0;r<4;r++)
        outv[tm][r] = accA[tm][r] - accG[tm][r] + bias;
  }
  __syncthreads();   // all sV1 reads done; arena reusable as sMIH

  // ---- epilogue: write out (bf16, K=64 layout) + per-wave tension partials
  {
    int col = jo2 + l15;
    float p[4][4];
    #pragma unroll
    for (int tm=0;tm<4;tm++){
      #pragma unroll
      for (int r=0;r<4;r++){
        int row = tm*16 + lg*4 + r;
        float o = outv[tm][r];
        int byte = (row*128 + col*2) ^ ((row&7)<<4);
        *(ushort*)((char*)sMIH + byte) = f2bf(o);
        p[tm][r] = o*o;
      }
    }
    #pragma unroll
    for (int off=1; off<16; off<<=1)
      #pragma unroll
      for (int tm=0;tm<4;tm++)
        #pragma unroll
        for (int r=0;r<4;r++) p[tm][r] += __shfl_xor(p[tm][r], off);
    if (l15 == 0){
      #pragma unroll
      for (int tm=0;tm<4;tm++)
        #pragma unroll
        for (int r=0;r<4;r++) sTS[w][tm*16 + lg*4 + r] = p[tm][r];
    }
  }
  __syncthreads();

  // ---- tension stats (wave 0; 64 lanes <-> 64 rows)
  if (w == 0){
    int row = lane;
    float t = (sTS[0][row] + sTS[1][row] + sTS[2][row] + sTS[3][row]) * (1.0f/64.0f);
    sT[row] = t;
    bool valid = row < nvalid;
    float m2 = valid ? t : -1.f;
    #pragma unroll
    for (int off=1; off<64; off<<=1) m2 = fmaxf(m2, __shfl_xor(m2, off));
    float e  = valid ? __expf(t - m2) : 0.f;
    float st = valid ? t : 0.f;
    float se = e, ss = st;
    #pragma unroll
    for (int off=1; off<64; off<<=1){ se += __shfl_xor(se, off); ss += __shfl_xor(ss, off); }
    sE[row] = e;
    if (lane == 0){
      float* rec = recs + (size_t)blockIdx.x*66;
      rec[0] = m2; rec[1] = se;
      atomicMax(tmax_u, __float_as_uint(m2));   // t >= 0
      atomicAdd(tsum, ss);
    }
  }
  __syncthreads();

  // ---- block-local softmax numerator (from registers)
  {
    float np = 0.f;
    #pragma unroll
    for (int tm=0;tm<4;tm++)
      #pragma unroll
      for (int r=0;r<4;r++)
        np += sE[tm*16 + lg*4 + r] * outv[tm][r];
    np += __shfl_xor(np, 16);
    np += __shfl_xor(np, 32);
    if (lg == 0) recs[(size_t)blockIdx.x*66 + 2 + jo2 + l15] = np;
  }

  // ---- faction bookkeeping (block-level)
  int lastrow = nvalid;
  if (base + lastrow > nffs) lastrow = nffs - base;
  int f0 = (fs > 0 && base < nffs) ? base / fs : 0;
  bool onefac = (lastrow <= 0) || ((base + lastrow - 1) / fs == f0);

  // ---- GRU, gate-batched: wave w -> hidden cols [w*32, w*32+32)
  {
    int jo3 = w*32;
    int ntb = 2*w;     // N-tile base within each gate's 8-tile group
    f32x4 aR[4][2], aZ[4][2], aN[4][2], aI[4][2];
    #pragma unroll
    for (int tm=0;tm<4;tm++)
      #pragma unroll
      for (int tn=0;tn<2;tn++){
        aR[tm][tn]=(f32x4)0.f; aZ[tm][tn]=(f32x4)0.f;
        aN[tm][tn]=(f32x4)0.f; aI[tm][tn]=(f32x4)0.f;
      }

    // K=128 over sH: gates r, z, hn share A fragments
    #pragma unroll
    for (int ks=0; ks<4; ks++){
      bf16x8 a[4];
      #pragma unroll
      for (int tm=0;tm<4;tm++){
        int row = tm*16 + l15;
        a[tm] = lds_ld8(sH, (row*256 + ks*64 + lg*16) ^ ((row&7)<<4));
      }
      bf16x8 bR[2], bZ[2], bN[2];
      #pragma unroll
      for (int tn=0;tn<2;tn++){
        bR[tn] = *(const bf16x8*)(Whf + ((((     ntb+tn)*4 + ks)*64 + lane)<<3));
        bZ[tn] = *(const bf16x8*)(Whf + ((((8  + ntb+tn)*4 + ks)*64 + lane)<<3));
        bN[tn] = *(const bf16x8*)(Whf + ((((16 + ntb+tn)*4 + ks)*64 + lane)<<3));
      }
      #pragma unroll
      for (int tm=0;tm<4;tm++)
        #pragma unroll
        for (int tn=0;tn<2;tn++){
          aR[tm][tn] = MFMA16(a[tm], bR[tn], aR[tm][tn]);
          aZ[tm][tn] = MFMA16(a[tm], bZ[tn], aZ[tm][tn]);
          aN[tm][tn] = MFMA16(a[tm], bN[tn], aN[tm][tn]);
        }
    }
    // K=64 over sMIH: gates r, z, inn share A fragments
    #pragma unroll
    for (int ks=0; ks<2; ks++){
      bf16x8 a[4];
      #pragma unroll
      for (int tm=0;tm<4;tm++){
        int row = tm*16 + l15;
        a[tm] = lds_ld8(sMIH, (row*128 + ks*64 + lg*16) ^ ((row&7)<<4));
      }
      bf16x8 bR[2], bZ[2], bI[2];
      #pragma unroll
      for (int tn=0;tn<2;tn++){
        bR[tn] = *(const bf16x8*)(Wgf + ((((     ntb+tn)*2 + ks)*64 + lane)<<3));
        bZ[tn] = *(const bf16x8*)(Wgf + ((((8  + ntb+tn)*2 + ks)*64 + lane)<<3));
        bI[tn] = *(const bf16x8*)(Wgf + ((((16 + ntb+tn)*2 + ks)*64 + lane)<<3));
      }
      #pragma unroll
      for (int tm=0;tm<4;tm++)
        #pragma unroll
        for (int tn=0;tn<2;tn++){
          aR[tm][tn] = MFMA16(a[tm], bR[tn], aR[tm][tn]);
          aZ[tm][tn] = MFMA16(a[tm], bZ[tn], aZ[tm][tn]);
          aI[tm][tn] = MFMA16(a[tm], bI[tn], aI[tm][tn]);
        }
    }

    // ---- epilogue: gate math + direct scatter + faction sums
    #pragma unroll
    for (int tn=0;tn<2;tn++){
      int col = jo3 + tn*16 + l15;
      float bR0 = brz[col],      wR = w64[col];
      float bZ0 = brz[128+col],  wZ = w64[128+col];
      float bI0 = bih[256+col],  wI = w64[256+col];
      float bN0 = bhh[256+col];
      float fsum = 0.f;
      #pragma unroll
      for (int tm=0;tm<4;tm++){
        #pragma unroll
        for (int r=0;r<4;r++){
          int row = tm*16 + lg*4 + r;
          float t = sT[row];
          float rr = sigmoidf_(aR[tm][tn][r] + bR0 + t*wR);
          float zz = sigmoidf_(aZ[tm][tn][r] + bZ0 + t*wZ);
          float nnv = tanhf_(aI[tm][tn][r] + bI0 + t*wI + rr*(aN[tm][tn][r] + bN0));
          int hb = (row*256 + col*2) ^ ((row&7)<<4);
          float hv = bf2f(*(const ushort*)((const char*)sH + hb));
          float v = (1.f - zz)*nnv + zz*hv;
          if (row < nvalid) nh[(size_t)sIdx[row]*128 + col] = v;
          if (onefac){
            if (row < lastrow) fsum += v;
          } else if (row < lastrow){
            atomicAdd(&facsum[((base+row)/fs)*128 + col], v);
          }
        }
      }
      if (onefac && lastrow > 0){
        fsum += __shfl_xor(fsum, 16);
        fsum += __shfl_xor(fsum, 32);
        if (lg == 0) atomicAdd(&facsum[f0*128 + col], fsum);
      }
    }
  }
}

// ---------- combine per-block softmax records ----------
__global__ void k_comb1(const float* __restrict__ recs, int nrec,
                        const unsigned* __restrict__ tmax_u,
                        float* __restrict__ num, float* __restrict__ S){
  int tid = threadIdx.x;
  int c = tid & 63, rg = tid >> 6;
  float M = __uint_as_float(*tmax_u);
  float acc = 0.f, sacc = 0.f;
  for (int r = blockIdx.x*4 + rg; r < nrec; r += gridDim.x*4){
    const float* rec = recs + (size_t)r*66;
    float e = __expf(rec[0] - M);
    acc += e * rec[2+c];
    if (c == 0) sacc += e * rec[1];
  }
  __shared__ float sn[4][64];
  __shared__ float ss[4];
  sn[rg][c] = acc;
  if (c == 0) ss[rg] = sacc;
  __syncthreads();
  if (tid < 64) atomicAdd(&num[tid], sn[0][tid]+sn[1][tid]+sn[2][tid]+sn[3][tid]);
  if (tid == 64) atomicAdd(S, ss[0]+ss[1]+ss[2]+ss[3]);
}

// ---------- finalize combined / mean_tension / faction means ----------
__global__ void k_final(const float* __restrict__ num, const float* __restrict__ S,
                        const float* __restrict__ tsum, const float* __restrict__ facsum,
                        float* __restrict__ out, float* __restrict__ go, float* __restrict__ fmn,
                        int n, int n_f, int fs){
  int tid = threadIdx.x;
  if (tid < 64) out[tid] = num[tid] / *S;
  else if (tid == 64) out[64] = *tsum / (float)n;
  if (tid >= 128 && n_f >= 2){
    int j = tid - 128;
    float s = 0.f;
    for (int f=0; f<n_f; f++){
      float v = facsum[f*128+j];
      s += v;
      fmn[f*128+j] = v / (float)fs;
    }
    go[j] = s / (float)(n_f*fs);
  }
}

// ---------- fused post-pass: copy non-alive rows + faction RMW on alive rows ----------
__global__ void k_post(const float* __restrict__ hid, const int* __restrict__ iflags,
                       const float* __restrict__ fmn, const float* __restrict__ go,
                       const int* __restrict__ step_p,
                       float* __restrict__ nh, int fs, int dc, int nffs, int total){
  bool debate = (*step_p > 5);
  int stride = gridDim.x*blockDim.x;
  for (int idx = blockIdx.x*blockDim.x + threadIdx.x; idx < total; idx += stride){
    int c = idx >> 5, q = idx & 31, j0 = q*4;
    size_t off = (size_t)c*128 + j0;
    int fl = iflags[c];
    if (fl == 0){
      float4 h4 = *(const float4*)(hid + off);
      nh[off] = h4.x; nh[off+1] = h4.y; nh[off+2] = h4.z; nh[off+3] = h4.w;
    } else {
      int i = fl - 1;
      if (i < nffs){
        float v0 = nh[off], v1 = nh[off+1], v2 = nh[off+2], v3 = nh[off+3];
        int f = i / fs;
        float4 fm4 = *(const float4*)(fmn + f*128 + j0);
        v0 = 0.85f*v0 + 0.15f*fm4.x;
        v1 = 0.85f*v1 + 0.15f*fm4.y;
        v2 = 0.85f*v2 + 0.15f*fm4.z;
        v3 = 0.85f*v3 + 0.15f*fm4.w;
        if (debate && (i - f*fs) < dc){
          float4 g4 = *(const float4*)(go + j0);
          v0 = 0.85f*v0 + 0.15f*g4.x;
          v1 = 0.85f*v1 + 0.15f*g4.y;
          v2 = 0.85f*v2 + 0.15f*g4.z;
          v3 = 0.85f*v3 + 0.15f*g4.w;
        }
        nh[off] = v0; nh[off+1] = v1; nh[off+2] = v2; nh[off+3] = v3;
      }
      // alive beyond faction region: value already correct in nh
    }
  }
}

extern "C" void kernel_launch(void* const* d_in, const int* in_sizes, int n_in,
                              void* d_out, int out_size, void* d_ws, size_t ws_size,
                              hipStream_t stream){
  const float* x    = (const float*)d_in[0];
  const float* hid  = (const float*)d_in[1];
  const float* Wa1  = (const float*)d_in[2];
  const float* ba1  = (const float*)d_in[3];
  const float* Wa2  = (const float*)d_in[4];
  const float* ba2  = (const float*)d_in[5];
  const float* Wg1  = (const float*)d_in[6];
  const float* bg1  = (const float*)d_in[7];
  const float* Wg2  = (const float*)d_in[8];
  const float* bg2  = (const float*)d_in[9];
  const float* Wih  = (const float*)d_in[10];
  const float* Whh  = (const float*)d_in[11];
  const float* bih  = (const float*)d_in[12];
  const float* bhh  = (const float*)d_in[13];
  const int*   alive= (const int*)d_in[14];
  const int*   step = (const int*)d_in[15];

  int n = in_sizes[14];
  int n_cells = in_sizes[1] / 128;
  int n_f = (n/2 < 8) ? n/2 : 8;
  int fs   = (n_f >= 2) ? n / n_f : 0;
  int nffs = (n_f >= 2) ? n_f * fs : 0;
  int dc   = (fs/4 > 1) ? fs/4 : 1;
  int nblocks = (n + TMC - 1) / TMC;

  float* out = (float*)d_out;
  float* nh  = out + 65;          // new_hiddens region (4B-aligned only!)
  float* ws  = (float*)d_ws;

  float* xab   = ws + 0;          // 256
  float* b2d   = ws + 256;        // 64
  float* brz   = ws + 320;        // 256
  float* facs  = ws + 576;        // 1024
  float* num   = ws + 1600;       // 64
  float* Ssum  = ws + 1664;       // 1
  float* tsum  = ws + 1665;       // 1
  unsigned* tmax_u = (unsigned*)(ws + 1666);  // 1 (+1 pad)
  float* go    = ws + 1668;       // 128
  float* fmn   = ws + 1796;       // 1024
  float* w64   = ws + 2820;       // 384
  float* recs  = ws + 3204;       // nblocks*66
  int recs_end = 3204 + ((nblocks*66 + 3) & ~3);
  int* iflags  = (int*)(ws + recs_end);                  // n_cells
  int woff = (recs_end + n_cells + 3) & ~3;
  ushort* W1f  = (ushort*)(ws + woff);                   // 256*128 bf16 = 16384 f
  ushort* W2f  = (ushort*)(ws + woff + 16384);           // 128*128 bf16 = 8192 f
  ushort* Wgf  = (ushort*)(ws + woff + 24576);           // 384*64  bf16 = 12288 f
  ushort* Whf  = (ushort*)(ws + woff + 36864);           // 384*128 bf16 = 24576 f

  // zero atomic accumulators (facs..tmax+pad) and iflags
  hipMemsetAsync(ws + 576, 0, 1092*sizeof(float), stream);
  hipMemsetAsync(iflags, 0, (size_t)n_cells*sizeof(int), stream);

  k_pre<<<1,256,0,stream>>>(x, Wa1, ba1, Wg1, bg1, ba2, bg2, bih, bhh, xab, b2d, brz);
  k_pack<<<256,256,0,stream>>>(Wa1, Wg1, Wa2, Wg2, Wih, Whh, W1f, W2f, Wgf, Whf, w64);
  k_mark<<<(n+255)/256,256,0,stream>>>(alive, iflags, n);
  k_main<<<nblocks,256,0,stream>>>(hid, alive, W1f, W2f, Wgf, Whf, w64, xab, b2d, brz,
                                   bih, bhh, nh, facs, recs, tmax_u, tsum,
                                   n, fs, nffs);
  k_comb1<<<64,256,0,stream>>>(recs, nblocks, tmax_u, num, Ssum);
  k_final<<<1,256,0,stream>>>(num, Ssum, tsum, facs, out, go, fmn, n, n_f, fs);
  k_post<<<2048,256,0,stream>>>(hid, iflags, fmn, go, step, nh, fs, dc, nffs, n_cells*32);
}